// Round 4
// baseline (62.906 us; speedup 1.0000x reference)
//
#include <hip/hip_runtime.h>
#include <math.h>

#define N_PTS 16384
#define PBLK 512                  // p points per k_nn block (256 thr x 2)
#define GCHUNK 256                // g points per k_nn block
#define NPBLK (N_PTS / PBLK)      // 32
#define NGCHUNK (N_PTS / GCHUNK)  // 64

// Monotone float->u32 encoding so unsigned min == float min (finite values).
__device__ __forceinline__ unsigned enc_f32(float f) {
    unsigned b = __float_as_uint(f);
    return (b & 0x80000000u) ? ~b : (b | 0x80000000u);
}
__device__ __forceinline__ float dec_f32(unsigned k) {
    unsigned b = (k & 0x80000000u) ? (k & 0x7fffffffu) : ~k;
    return __uint_as_float(b);
}

// Prep: pws = (-2px,-2py,-2pz,|p|^2), gws = (gx,gy,gz,|g|^2); optional key init.
__global__ __launch_bounds__(256) void k_prep(
        const float* __restrict__ R, const float* __restrict__ t,
        const float* __restrict__ m, const float* __restrict__ g,
        float4* __restrict__ pws, float4* __restrict__ gws,
        unsigned* __restrict__ keys, int init_keys) {
    int n = blockIdx.x * 256 + threadIdx.x;
    float mx = m[3*n+0], my = m[3*n+1], mz = m[3*n+2];
    float px = fmaf(R[0], mx, fmaf(R[1], my, R[2]*mz)) + t[0];
    float py = fmaf(R[3], mx, fmaf(R[4], my, R[5]*mz)) + t[1];
    float pz = fmaf(R[6], mx, fmaf(R[7], my, R[8]*mz)) + t[2];
    float pp = fmaf(px,px,fmaf(py,py,pz*pz));
    pws[n] = make_float4(-2.f*px, -2.f*py, -2.f*pz, pp);
    float gx = g[3*n+0], gy = g[3*n+1], gz = g[3*n+2];
    gws[n] = make_float4(gx, gy, gz, fmaf(gx,gx,fmaf(gy,gy,gz*gz)));
    if (init_keys) keys[n] = 0xFFFFFFFFu;
}

// NN: g via wave-uniform loads (scalar/SMEM pipe), p per-lane in VGPRs.
// No LDS. 10 VALU per 2g x 2p step = 2.5 inst/pair.
template<bool ATOMIC>
__global__ __launch_bounds__(256, 8) void k_nn(
        const float4* __restrict__ pws, const float4* __restrict__ gws,
        float* __restrict__ partial /* or unsigned keys when ATOMIC */) {
    const int tid = threadIdx.x;
    const int pbase = blockIdx.x * PBLK;
    const int g0 = blockIdx.y * GCHUNK;

    float4 p0 = pws[pbase + tid];            // (-2x,-2y,-2z,pp)
    float4 p1 = pws[pbase + 256 + tid];

    float sm0 = 3.4e38f, sm1 = 3.4e38f;
    #pragma unroll 8
    for (int gi = 0; gi < GCHUNK; gi += 2) {
        float4 a = gws[g0 + gi];             // uniform -> s_load (SMEM pipe)
        float4 b = gws[g0 + gi + 1];
        float s0a = fmaf(p0.x, a.x, fmaf(p0.y, a.y, fmaf(p0.z, a.z, a.w)));
        float s0b = fmaf(p0.x, b.x, fmaf(p0.y, b.y, fmaf(p0.z, b.z, b.w)));
        float s1a = fmaf(p1.x, a.x, fmaf(p1.y, a.y, fmaf(p1.z, a.z, a.w)));
        float s1b = fmaf(p1.x, b.x, fmaf(p1.y, b.y, fmaf(p1.z, b.z, b.w)));
        sm0 = fminf(sm0, fminf(s0a, s0b));   // -> v_min3_f32
        sm1 = fminf(sm1, fminf(s1a, s1b));
    }
    sm0 += p0.w;   // min d2 for this chunk
    sm1 += p1.w;

    if (ATOMIC) {
        unsigned* keys = (unsigned*)partial;
        atomicMin(&keys[pbase + tid],       enc_f32(sm0));
        atomicMin(&keys[pbase + 256 + tid], enc_f32(sm1));
    } else {
        partial[blockIdx.y * N_PTS + pbase + tid]       = sm0;
        partial[blockIdx.y * N_PTS + pbase + 256 + tid] = sm1;
    }
}

// Per-point min over chunks -> sqrt -> block partial sum.
template<bool ATOMIC>
__global__ __launch_bounds__(256) void k_finalize(
        const float* __restrict__ R, const float* __restrict__ t,
        const float* __restrict__ m, const float* __restrict__ g,
        const float* __restrict__ partial, const int* __restrict__ midx,
        float* __restrict__ psum) {
    const int tid = threadIdx.x;
    const int n = blockIdx.x * 256 + tid;
    const bool sym = (midx[0] == 0);
    float dis;
    if (sym) {
        float d2;
        if (ATOMIC) {
            d2 = dec_f32(((const unsigned*)partial)[n]);
        } else {
            d2 = 3.4e38f;
            #pragma unroll 8
            for (int c = 0; c < NGCHUNK; ++c)
                d2 = fminf(d2, partial[c * N_PTS + n]);
        }
        dis = sqrtf(fmaxf(d2, 0.f));
    } else {
        float mx=m[3*n+0], my=m[3*n+1], mz=m[3*n+2];
        float px = fmaf(R[0],mx,fmaf(R[1],my,R[2]*mz)) + t[0] - g[3*n+0];
        float py = fmaf(R[3],mx,fmaf(R[4],my,R[5]*mz)) + t[1] - g[3*n+1];
        float pz = fmaf(R[6],mx,fmaf(R[7],my,R[8]*mz)) + t[2] - g[3*n+2];
        dis = sqrtf(fmaf(px,px,fmaf(py,py,pz*pz)));
    }
    float acc = dis;
    #pragma unroll
    for (int off = 32; off > 0; off >>= 1) acc += __shfl_down(acc, off, 64);
    __shared__ float sred[4];
    if ((tid & 63) == 0) sred[tid >> 6] = acc;
    __syncthreads();
    if (tid == 0) psum[blockIdx.x] = (sred[0] + sred[1]) + (sred[2] + sred[3]);
}

// Final reduction of 64 partial sums -> mean.
__global__ void k_final(const float* __restrict__ psum, float* __restrict__ out) {
    float v = psum[threadIdx.x];
    #pragma unroll
    for (int off = 32; off > 0; off >>= 1) v += __shfl_down(v, off, 64);
    if (threadIdx.x == 0) out[0] = v / (float)N_PTS;
}

extern "C" void kernel_launch(void* const* d_in, const int* in_sizes, int n_in,
                              void* d_out, int out_size, void* d_ws, size_t ws_size,
                              hipStream_t stream) {
    const float* R   = (const float*)d_in[0];
    const float* t   = (const float*)d_in[1];
    const float* m   = (const float*)d_in[2];
    const float* g   = (const float*)d_in[3];
    const int* midx  = (const int*)d_in[4];

    char* ws = (char*)d_ws;
    float* out = (float*)d_out;

    float4* pws = (float4*)(ws + 0);          // 256 KB
    float4* gws = (float4*)(ws + 262144);     // 256 KB
    char*   rest = ws + 524288;

    const size_t partial_bytes = (size_t)NGCHUNK * N_PTS * 4;   // 4 MB
    const bool use_partial = ws_size >= 524288 + partial_bytes + 1024;

    if (use_partial) {
        float* partial = (float*)rest;
        float* psum    = (float*)(rest + partial_bytes);
        k_prep<<<dim3(N_PTS/256), dim3(256), 0, stream>>>(R, t, m, g, pws, gws, nullptr, 0);
        k_nn<false><<<dim3(NPBLK, NGCHUNK), dim3(256), 0, stream>>>(pws, gws, partial);
        k_finalize<false><<<dim3(N_PTS/256), dim3(256), 0, stream>>>(R, t, m, g, partial, midx, psum);
        k_final<<<dim3(1), dim3(64), 0, stream>>>(psum, out);
    } else {
        unsigned* keys = (unsigned*)rest;
        float* psum    = (float*)(rest + N_PTS * 4);
        k_prep<<<dim3(N_PTS/256), dim3(256), 0, stream>>>(R, t, m, g, pws, gws, keys, 1);
        k_nn<true><<<dim3(NPBLK, NGCHUNK), dim3(256), 0, stream>>>(pws, gws, (float*)keys);
        k_finalize<true><<<dim3(N_PTS/256), dim3(256), 0, stream>>>(R, t, m, g, (float*)keys, midx, psum);
        k_final<<<dim3(1), dim3(64), 0, stream>>>(psum, out);
    }
}

// Round 5
// 59.725 us; speedup vs baseline: 1.0533x; 1.0533x over previous
//
#include <hip/hip_runtime.h>
#include <math.h>

#define N_PTS 16384
#define P 8                        // p points per thread in k_nn
#define PBLK (256 * P)             // 2048 p per block
#define NPBLK (N_PTS / PBLK)       // 8
#define GCHUNK 64                  // g points per block
#define NGCHUNK (N_PTS / GCHUNK)   // 256
#define NFBLK 256                  // finalize blocks (64 points each)
#define SCALE 16777216.0           // 2^24 fixed-point for deterministic sum

// Monotone float->u32 encoding so unsigned min == float min (finite values).
__device__ __forceinline__ unsigned enc_f32(float f) {
    unsigned b = __float_as_uint(f);
    return (b & 0x80000000u) ? ~b : (b | 0x80000000u);
}
__device__ __forceinline__ float dec_f32(unsigned k) {
    unsigned b = (k & 0x80000000u) ? (k & 0x7fffffffu) : ~k;
    return __uint_as_float(b);
}

// Prep: pws = (-2px,-2py,-2pz,|p|^2), gws = (gx,gy,gz,|g|^2);
// zero the fixed-point accumulator + completion counter; optional key init.
__global__ __launch_bounds__(256) void k_prep(
        const float* __restrict__ R, const float* __restrict__ t,
        const float* __restrict__ m, const float* __restrict__ g,
        float4* __restrict__ pws, float4* __restrict__ gws,
        unsigned long long* __restrict__ acc, unsigned* __restrict__ counter,
        unsigned* __restrict__ keys, int init_keys) {
    int n = blockIdx.x * 256 + threadIdx.x;
    if (n == 0) { *acc = 0ull; *counter = 0u; }
    if (init_keys) keys[n] = 0xFFFFFFFFu;
    float mx = m[3*n+0], my = m[3*n+1], mz = m[3*n+2];
    float px = fmaf(R[0], mx, fmaf(R[1], my, R[2]*mz)) + t[0];
    float py = fmaf(R[3], mx, fmaf(R[4], my, R[5]*mz)) + t[1];
    float pz = fmaf(R[6], mx, fmaf(R[7], my, R[8]*mz)) + t[2];
    float pp = fmaf(px,px,fmaf(py,py,pz*pz));
    pws[n] = make_float4(-2.f*px, -2.f*py, -2.f*pz, pp);
    float gx = g[3*n+0], gy = g[3*n+1], gz = g[3*n+2];
    gws[n] = make_float4(gx, gy, gz, fmaf(gx,gx,fmaf(gy,gy,gz*gz)));
}

// NN: g via wave-uniform SMEM loads, 8 p per thread in VGPRs.
// Per 2-g group: 48 fma + 8 min3 + ~2 mov -> SMEM latency hidden by ILP.
template<bool ATOMIC>
__global__ __launch_bounds__(256, 4) void k_nn(
        const float4* __restrict__ pws, const float4* __restrict__ gws,
        float* __restrict__ partial /* or unsigned keys when ATOMIC */) {
    const int tid = threadIdx.x;
    const int pbase = blockIdx.x * PBLK;
    const int g0 = blockIdx.y * GCHUNK;

    float px[P], py[P], pz[P], pp[P], sm[P];
    #pragma unroll
    for (int k = 0; k < P; ++k) {
        float4 p = pws[pbase + k*256 + tid];   // (-2x,-2y,-2z,|p|^2)
        px[k] = p.x; py[k] = p.y; pz[k] = p.z; pp[k] = p.w;
        sm[k] = 3.4e38f;
    }

    #pragma unroll 4
    for (int gi = 0; gi < GCHUNK; gi += 2) {
        float4 a = gws[g0 + gi];               // uniform -> s_load
        float4 b = gws[g0 + gi + 1];
        #pragma unroll
        for (int k = 0; k < P; ++k) {
            float sa = fmaf(px[k], a.x, fmaf(py[k], a.y, fmaf(pz[k], a.z, a.w)));
            float sb = fmaf(px[k], b.x, fmaf(py[k], b.y, fmaf(pz[k], b.z, b.w)));
            sm[k] = fminf(sm[k], fminf(sa, sb));   // -> v_min3_f32
        }
    }

    if (ATOMIC) {
        unsigned* keys = (unsigned*)partial;
        #pragma unroll
        for (int k = 0; k < P; ++k)
            atomicMin(&keys[pbase + k*256 + tid], enc_f32(sm[k] + pp[k]));
    } else {
        float* row = partial + (size_t)blockIdx.y * N_PTS + pbase + tid;
        #pragma unroll
        for (int k = 0; k < P; ++k)
            row[k*256] = sm[k] + pp[k];            // coalesced
    }
}

// Finalize: per-point min over 256 chunks (split 4-way across threads),
// sqrt, wave-sum, deterministic fixed-point atomicAdd; last block writes out.
template<bool ATOMIC>
__global__ __launch_bounds__(256) void k_fin(
        const float* __restrict__ R, const float* __restrict__ t,
        const float* __restrict__ m, const float* __restrict__ g,
        const float* __restrict__ partial, const int* __restrict__ midx,
        unsigned long long* __restrict__ acc, unsigned* __restrict__ counter,
        float* __restrict__ out) {
    const int tid = threadIdx.x;
    const bool sym = (midx[0] == 0);
    float dis = 0.f;

    if (sym) {
        if (ATOMIC) {
            if (tid < 64) {
                int n = blockIdx.x * 64 + tid;
                float d2 = dec_f32(((const unsigned*)partial)[n]);
                dis = sqrtf(fmaxf(d2, 0.f));
            }
        } else {
            const int n = blockIdx.x * 64 + (tid & 63);
            const int q = tid >> 6;                 // chunk quarter 0..3
            float v = 3.4e38f;
            #pragma unroll 8
            for (int i = 0; i < NGCHUNK/4; ++i)
                v = fminf(v, partial[(size_t)(q*(NGCHUNK/4) + i) * N_PTS + n]);
            __shared__ float sv[256];
            sv[tid] = v;
            __syncthreads();
            if (tid < 64) {
                float d2 = fminf(fminf(sv[tid], sv[tid+64]),
                                 fminf(sv[tid+128], sv[tid+192]));
                dis = sqrtf(fmaxf(d2, 0.f));
            }
        }
    } else {
        if (tid < 64) {
            int n = blockIdx.x * 64 + tid;
            float mx=m[3*n+0], my=m[3*n+1], mz=m[3*n+2];
            float dx = fmaf(R[0],mx,fmaf(R[1],my,R[2]*mz)) + t[0] - g[3*n+0];
            float dy = fmaf(R[3],mx,fmaf(R[4],my,R[5]*mz)) + t[1] - g[3*n+1];
            float dz = fmaf(R[6],mx,fmaf(R[7],my,R[8]*mz)) + t[2] - g[3*n+2];
            dis = sqrtf(fmaf(dx,dx,fmaf(dy,dy,dz*dz)));
        }
    }

    if (tid < 64) {                               // wave 0 exactly
        #pragma unroll
        for (int off = 32; off > 0; off >>= 1) dis += __shfl_down(dis, off, 64);
        if (tid == 0) {
            atomicAdd(acc, (unsigned long long)((double)dis * SCALE + 0.5));
            __threadfence();
            unsigned old = atomicAdd(counter, 1u);
            if (old == NFBLK - 1) {
                __threadfence();
                unsigned long long a = atomicAdd(acc, 0ull);
                out[0] = (float)((double)a / SCALE / (double)N_PTS);
            }
        }
    }
}

extern "C" void kernel_launch(void* const* d_in, const int* in_sizes, int n_in,
                              void* d_out, int out_size, void* d_ws, size_t ws_size,
                              hipStream_t stream) {
    const float* R   = (const float*)d_in[0];
    const float* t   = (const float*)d_in[1];
    const float* m   = (const float*)d_in[2];
    const float* g   = (const float*)d_in[3];
    const int* midx  = (const int*)d_in[4];

    char* ws = (char*)d_ws;
    float* out = (float*)d_out;

    const size_t partial_bytes = (size_t)NGCHUNK * N_PTS * 4;   // 16 MB
    const bool use_partial = ws_size >= partial_bytes + (1u<<20);

    if (use_partial) {
        float*              partial = (float*)ws;
        unsigned long long* acc     = (unsigned long long*)(ws + partial_bytes);
        unsigned*           counter = (unsigned*)(ws + partial_bytes + 8);
        float4*             pws     = (float4*)(ws + partial_bytes + 64);
        float4*             gws     = (float4*)(ws + partial_bytes + 64 + 262144);

        k_prep<<<dim3(N_PTS/256), dim3(256), 0, stream>>>(
            R, t, m, g, pws, gws, acc, counter, nullptr, 0);
        k_nn<false><<<dim3(NPBLK, NGCHUNK), dim3(256), 0, stream>>>(pws, gws, partial);
        k_fin<false><<<dim3(NFBLK), dim3(256), 0, stream>>>(
            R, t, m, g, partial, midx, acc, counter, out);
    } else {
        unsigned*           keys    = (unsigned*)ws;
        unsigned long long* acc     = (unsigned long long*)(ws + 65536);
        unsigned*           counter = (unsigned*)(ws + 65536 + 8);
        float4*             pws     = (float4*)(ws + 65536 + 64);
        float4*             gws     = (float4*)(ws + 65536 + 64 + 262144);

        k_prep<<<dim3(N_PTS/256), dim3(256), 0, stream>>>(
            R, t, m, g, pws, gws, acc, counter, keys, 1);
        k_nn<true><<<dim3(NPBLK, NGCHUNK), dim3(256), 0, stream>>>(pws, gws, (float*)keys);
        k_fin<true><<<dim3(NFBLK), dim3(256), 0, stream>>>(
            R, t, m, g, (float*)keys, midx, acc, counter, out);
    }
}

// Round 6
// 35.569 us; speedup vs baseline: 1.7686x; 1.6791x over previous
//
#include <hip/hip_runtime.h>
#include <math.h>

#define N_PTS 16384
#define WAVE_P 128                 // p-cols per wave (4 B-frags x 32)
#define BLK_P  512                 // p per block (4 waves)
#define NPB    (N_PTS / BLK_P)     // 32
#define CHUNK_G 512                // g per chunk
#define NCH    (N_PTS / CHUNK_G)   // 32
#define NGROUP (CHUNK_G / 32)      // 16 A-groups per chunk
#define NROWS  (NCH * 2)           // 64 partial rows (chunk x lane-half)
#define NFBLK 256
#define SCALE 16777216.0

typedef __attribute__((ext_vector_type(8)))  short short8_t;
typedef __attribute__((ext_vector_type(16))) float f32x16;

// --- bf16 helpers (round-to-nearest-even) ---
__device__ __forceinline__ unsigned short bf_rn(float x) {
    unsigned u = __float_as_uint(x);
    unsigned r = (u + 0x7fffu + ((u >> 16) & 1u)) >> 16;
    return (unsigned short)r;
}
__device__ __forceinline__ float bf_up(unsigned short s) {
    return __uint_as_float(((unsigned)s) << 16);
}
// Monotone float->u32 for atomic-min fallback.
__device__ __forceinline__ unsigned enc_f32(float f) {
    unsigned b = __float_as_uint(f);
    return (b & 0x80000000u) ? ~b : (b | 0x80000000u);
}
__device__ __forceinline__ float dec_f32(unsigned k) {
    unsigned b = (k & 0x80000000u) ? (k & 0x7fffffffu) : ~k;
    return __uint_as_float(b);
}

// Prep: pws=(-2px,-2py,-2pz,|p|^2), gws=(g,|g|^2), bf16-split MFMA operand
// rows paA (g side) and pbB (p side), zero acc/counter, optional keys.
__global__ __launch_bounds__(256) void k_prep(
        const float* __restrict__ R, const float* __restrict__ t,
        const float* __restrict__ m, const float* __restrict__ g,
        float4* __restrict__ pws, float4* __restrict__ gws,
        unsigned short* __restrict__ paA, unsigned short* __restrict__ pbB,
        unsigned long long* __restrict__ acc, unsigned* __restrict__ counter,
        unsigned* __restrict__ keys, int init_keys) {
    int n = blockIdx.x * 256 + threadIdx.x;
    if (n == 0) { *acc = 0ull; *counter = 0u; }
    if (init_keys) keys[n] = 0xFFFFFFFFu;

    float mx = m[3*n+0], my = m[3*n+1], mz = m[3*n+2];
    float px = fmaf(R[0], mx, fmaf(R[1], my, R[2]*mz)) + t[0];
    float py = fmaf(R[3], mx, fmaf(R[4], my, R[5]*mz)) + t[1];
    float pz = fmaf(R[6], mx, fmaf(R[7], my, R[8]*mz)) + t[2];
    float pp = fmaf(px,px,fmaf(py,py,pz*pz));
    pws[n] = make_float4(-2.f*px, -2.f*py, -2.f*pz, pp);
    float gx = g[3*n+0], gy = g[3*n+1], gz = g[3*n+2];
    float gg = fmaf(gx,gx,fmaf(gy,gy,gz*gz));
    gws[n] = make_float4(gx, gy, gz, gg);

    // hi/lo splits
    float Px = -2.f*px, Py = -2.f*py, Pz = -2.f*pz;
    unsigned short phx = bf_rn(Px), phy = bf_rn(Py), phz = bf_rn(Pz);
    unsigned short plx = bf_rn(Px - bf_up(phx)),
                   ply = bf_rn(Py - bf_up(phy)),
                   plz = bf_rn(Pz - bf_up(phz));
    unsigned short ghx = bf_rn(gx), ghy = bf_rn(gy), ghz = bf_rn(gz);
    unsigned short glx = bf_rn(gx - bf_up(ghx)),
                   gly = bf_rn(gy - bf_up(ghy)),
                   glz = bf_rn(gz - bf_up(ghz));
    unsigned short ggh = bf_rn(gg), ggl = bf_rn(gg - bf_up(ggh));
    const unsigned short one = 0x3F80;

    union { unsigned short u[16]; int4 v[2]; } A, B;
    // A (g row): gh gh gh | gh gh gh | gg_h gg_l | gl gl gl | 0...
    A.u[0]=ghx; A.u[1]=ghy; A.u[2]=ghz; A.u[3]=ghx; A.u[4]=ghy; A.u[5]=ghz;
    A.u[6]=ggh; A.u[7]=ggl; A.u[8]=glx; A.u[9]=gly; A.u[10]=glz;
    A.u[11]=0; A.u[12]=0; A.u[13]=0; A.u[14]=0; A.u[15]=0;
    // B (p col): ph ph ph | pl pl pl | 1 1 | ph ph ph | 0...
    B.u[0]=phx; B.u[1]=phy; B.u[2]=phz; B.u[3]=plx; B.u[4]=ply; B.u[5]=plz;
    B.u[6]=one; B.u[7]=one; B.u[8]=phx; B.u[9]=phy; B.u[10]=phz;
    B.u[11]=0; B.u[12]=0; B.u[13]=0; B.u[14]=0; B.u[15]=0;

    int4* pa = (int4*)(paA + (size_t)n * 16);
    int4* pb = (int4*)(pbB + (size_t)n * 16);
    pa[0] = A.v[0]; pa[1] = A.v[1];
    pb[0] = B.v[0]; pb[1] = B.v[1];
}

__device__ __forceinline__ float tree16(f32x16 d) {
    float a0 = fminf(d[0], d[1]),  a1 = fminf(d[2], d[3]);
    float a2 = fminf(d[4], d[5]),  a3 = fminf(d[6], d[7]);
    float a4 = fminf(d[8], d[9]),  a5 = fminf(d[10], d[11]);
    float a6 = fminf(d[12], d[13]), a7 = fminf(d[14], d[15]);
    float b0 = fminf(a0, a1), b1 = fminf(a2, a3);
    float b2 = fminf(a4, a5), b3 = fminf(a6, a7);
    return fminf(fminf(b0, b1), fminf(b2, b3));
}

// MFMA NN: each wave owns 128 p-cols (4 B-frags), loops 16 g-groups of its
// 512-g chunk: 1 A-frag load + 4 MFMA + min-trees. Stores per-(chunk,half) row.
__global__ __launch_bounds__(256, 4) void k_nn_mfma(
        const unsigned short* __restrict__ paA,
        const unsigned short* __restrict__ pbB,
        float* __restrict__ partial) {
    const int tid = threadIdx.x;
    const int wid = tid >> 6, l = tid & 63;
    const int lc = l & 31, lh = l >> 5;
    const int pbase = blockIdx.x * BLK_P + wid * WAVE_P;
    const int g0 = blockIdx.y * CHUNK_G;

    short8_t B0 = *(const short8_t*)(pbB + (size_t)(pbase +  0 + lc)*16 + lh*8);
    short8_t B1 = *(const short8_t*)(pbB + (size_t)(pbase + 32 + lc)*16 + lh*8);
    short8_t B2 = *(const short8_t*)(pbB + (size_t)(pbase + 64 + lc)*16 + lh*8);
    short8_t B3 = *(const short8_t*)(pbB + (size_t)(pbase + 96 + lc)*16 + lh*8);

    const f32x16 zc = {};          // permanent zero C operand
    float rm0 = 3.4e38f, rm1 = 3.4e38f, rm2 = 3.4e38f, rm3 = 3.4e38f;

    const unsigned short* aptr = paA + (size_t)(g0 + lc)*16 + lh*8;
    short8_t a = *(const short8_t*)aptr;
    #pragma unroll 2
    for (int gi = 0; gi < NGROUP; ++gi) {
        short8_t an = (gi + 1 < NGROUP)
                      ? *(const short8_t*)(aptr + (size_t)(gi + 1) * 32 * 16) : a;
        f32x16 d0 = __builtin_amdgcn_mfma_f32_32x32x16_bf16(a, B0, zc, 0, 0, 0);
        f32x16 d1 = __builtin_amdgcn_mfma_f32_32x32x16_bf16(a, B1, zc, 0, 0, 0);
        f32x16 d2 = __builtin_amdgcn_mfma_f32_32x32x16_bf16(a, B2, zc, 0, 0, 0);
        f32x16 d3 = __builtin_amdgcn_mfma_f32_32x32x16_bf16(a, B3, zc, 0, 0, 0);
        rm0 = fminf(rm0, tree16(d0));
        rm1 = fminf(rm1, tree16(d1));
        rm2 = fminf(rm2, tree16(d2));
        rm3 = fminf(rm3, tree16(d3));
        a = an;
    }

    float* row = partial + (size_t)(blockIdx.y * 2 + lh) * N_PTS + pbase + lc;
    row[0]  = rm0;
    row[32] = rm1;
    row[64] = rm2;
    row[96] = rm3;
}

// Vector fallback (atomic keys) for small ws.
__global__ __launch_bounds__(256, 4) void k_nn_vec(
        const float4* __restrict__ pws, const float4* __restrict__ gws,
        unsigned* __restrict__ keys) {
    const int tid = threadIdx.x;
    const int pbase = blockIdx.x * 2048;
    const int g0 = blockIdx.y * 64;
    float px[8], py[8], pz[8], pp[8], sm[8];
    #pragma unroll
    for (int k = 0; k < 8; ++k) {
        float4 p = pws[pbase + k*256 + tid];
        px[k]=p.x; py[k]=p.y; pz[k]=p.z; pp[k]=p.w; sm[k]=3.4e38f;
    }
    #pragma unroll 4
    for (int gi = 0; gi < 64; gi += 2) {
        float4 a = gws[g0 + gi];
        float4 b = gws[g0 + gi + 1];
        #pragma unroll
        for (int k = 0; k < 8; ++k) {
            float sa = fmaf(px[k], a.x, fmaf(py[k], a.y, fmaf(pz[k], a.z, a.w)));
            float sb = fmaf(px[k], b.x, fmaf(py[k], b.y, fmaf(pz[k], b.z, b.w)));
            sm[k] = fminf(sm[k], fminf(sa, sb));
        }
    }
    #pragma unroll
    for (int k = 0; k < 8; ++k)
        atomicMin(&keys[pbase + k*256 + tid], enc_f32(sm[k] + pp[k]));
}

// Finalize: per-point min over NROWS rows (+pp), sqrt, wave-sum, fixed-point
// atomic accumulate; last block writes the mean.
template<bool ATOMIC>
__global__ __launch_bounds__(256) void k_fin(
        const float* __restrict__ R, const float* __restrict__ t,
        const float* __restrict__ m, const float* __restrict__ g,
        const float4* __restrict__ pws,
        const float* __restrict__ partial, const int* __restrict__ midx,
        unsigned long long* __restrict__ acc, unsigned* __restrict__ counter,
        float* __restrict__ out) {
    const int tid = threadIdx.x;
    const bool sym = (midx[0] == 0);
    float dis = 0.f;

    if (sym) {
        if (ATOMIC) {
            if (tid < 64) {
                int n = blockIdx.x * 64 + tid;
                dis = sqrtf(fmaxf(dec_f32(((const unsigned*)partial)[n]), 0.f));
            }
        } else {
            const int n = blockIdx.x * 64 + (tid & 63);
            const int q = tid >> 6;                       // row quarter
            float v = 3.4e38f;
            #pragma unroll 4
            for (int i = 0; i < NROWS/4; ++i)
                v = fminf(v, partial[(size_t)(q*(NROWS/4) + i) * N_PTS + n]);
            __shared__ float sv[256];
            sv[tid] = v;
            __syncthreads();
            if (tid < 64) {
                float d2 = fminf(fminf(sv[tid], sv[tid+64]),
                                 fminf(sv[tid+128], sv[tid+192]));
                dis = sqrtf(fmaxf(pws[n].w + d2, 0.f));
            }
        }
    } else {
        if (tid < 64) {
            int n = blockIdx.x * 64 + tid;
            float mx=m[3*n+0], my=m[3*n+1], mz=m[3*n+2];
            float dx = fmaf(R[0],mx,fmaf(R[1],my,R[2]*mz)) + t[0] - g[3*n+0];
            float dy = fmaf(R[3],mx,fmaf(R[4],my,R[5]*mz)) + t[1] - g[3*n+1];
            float dz = fmaf(R[6],mx,fmaf(R[7],my,R[8]*mz)) + t[2] - g[3*n+2];
            dis = sqrtf(fmaf(dx,dx,fmaf(dy,dy,dz*dz)));
        }
    }

    if (tid < 64) {
        #pragma unroll
        for (int off = 32; off > 0; off >>= 1) dis += __shfl_down(dis, off, 64);
        if (tid == 0) {
            atomicAdd(acc, (unsigned long long)((double)dis * SCALE + 0.5));
            __threadfence();
            unsigned old = atomicAdd(counter, 1u);
            if (old == NFBLK - 1) {
                __threadfence();
                unsigned long long a = atomicAdd(acc, 0ull);
                out[0] = (float)((double)a / SCALE / (double)N_PTS);
            }
        }
    }
}

extern "C" void kernel_launch(void* const* d_in, const int* in_sizes, int n_in,
                              void* d_out, int out_size, void* d_ws, size_t ws_size,
                              hipStream_t stream) {
    const float* R   = (const float*)d_in[0];
    const float* t   = (const float*)d_in[1];
    const float* m   = (const float*)d_in[2];
    const float* g   = (const float*)d_in[3];
    const int* midx  = (const int*)d_in[4];

    char* ws = (char*)d_ws;
    float* out = (float*)d_out;

    const size_t partial_bytes = (size_t)NROWS * N_PTS * 4;   // 4 MB
    // layout: partial | acc/counter(64B) | pws 256K | gws 256K | paA 512K | pbB 512K
    unsigned long long* acc     = (unsigned long long*)(ws + partial_bytes);
    unsigned*           counter = (unsigned*)(ws + partial_bytes + 8);
    float4*         pws = (float4*)(ws + partial_bytes + 64);
    float4*         gws = (float4*)(ws + partial_bytes + 64 + 262144);
    unsigned short* paA = (unsigned short*)(ws + partial_bytes + 64 + 524288);
    unsigned short* pbB = (unsigned short*)(ws + partial_bytes + 64 + 524288 + 524288);
    const bool use_mfma = ws_size >= partial_bytes + 64 + 524288 + 1048576 + 4096;

    if (use_mfma) {
        float* partial = (float*)ws;
        k_prep<<<dim3(N_PTS/256), dim3(256), 0, stream>>>(
            R, t, m, g, pws, gws, paA, pbB, acc, counter, nullptr, 0);
        k_nn_mfma<<<dim3(NPB, NCH), dim3(256), 0, stream>>>(paA, pbB, partial);
        k_fin<false><<<dim3(NFBLK), dim3(256), 0, stream>>>(
            R, t, m, g, pws, partial, midx, acc, counter, out);
    } else {
        unsigned* keys = (unsigned*)ws;
        unsigned long long* acc2  = (unsigned long long*)(ws + 65536);
        unsigned*           cnt2  = (unsigned*)(ws + 65536 + 8);
        float4* pws2 = (float4*)(ws + 65536 + 64);
        float4* gws2 = (float4*)(ws + 65536 + 64 + 262144);
        unsigned short* paA2 = (unsigned short*)(ws + 65536 + 64 + 524288);
        unsigned short* pbB2 = paA2 + 16 * N_PTS;
        k_prep<<<dim3(N_PTS/256), dim3(256), 0, stream>>>(
            R, t, m, g, pws2, gws2, paA2, pbB2, acc2, cnt2, keys, 1);
        k_nn_vec<<<dim3(8, 256), dim3(256), 0, stream>>>(pws2, gws2, keys);
        k_fin<true><<<dim3(NFBLK), dim3(256), 0, stream>>>(
            R, t, m, g, pws2, (float*)keys, midx, acc2, cnt2, out);
    }
}

// Round 7
// 30.923 us; speedup vs baseline: 2.0343x; 1.1502x over previous
//
#include <hip/hip_runtime.h>
#include <math.h>

#define N_PTS 16384
#define WAVE_P 128                 // p-cols per wave (4 B-frags x 32)
#define BLK_P  512                 // p per block (4 waves)
#define NPB    (N_PTS / BLK_P)     // 32
#define CHUNK_G 512                // g per chunk
#define NCH    (N_PTS / CHUNK_G)   // 32
#define NGROUP (CHUNK_G / 32)      // 16 A-groups per chunk
#define NROWS  NCH                 // 32 partial rows (halves merged in-kernel)
#define NFBLK 256
#define SCALE 16777216.0

typedef __attribute__((ext_vector_type(8)))  short short8_t;
typedef __attribute__((ext_vector_type(16))) float f32x16;

// --- bf16 helpers (round-to-nearest-even) ---
__device__ __forceinline__ unsigned short bf_rn(float x) {
    unsigned u = __float_as_uint(x);
    unsigned r = (u + 0x7fffu + ((u >> 16) & 1u)) >> 16;
    return (unsigned short)r;
}
__device__ __forceinline__ float bf_up(unsigned short s) {
    return __uint_as_float(((unsigned)s) << 16);
}
// Monotone float->u32 for atomic-min fallback.
__device__ __forceinline__ unsigned enc_f32(float f) {
    unsigned b = __float_as_uint(f);
    return (b & 0x80000000u) ? ~b : (b | 0x80000000u);
}
__device__ __forceinline__ float dec_f32(unsigned k) {
    unsigned b = (k & 0x80000000u) ? (k & 0x7fffffffu) : ~k;
    return __uint_as_float(b);
}
__device__ __forceinline__ float min3f(float a, float b, float c) {
    return fminf(fminf(a, b), c);      // -> v_min3_f32
}

// Prep: pws=(-2p,|p|^2), gws=(g,|g|^2), pp[], bf16-split MFMA operand rows
// paA (g side) / pbB (p side); zero acc/counter; optional keys.
__global__ __launch_bounds__(256) void k_prep(
        const float* __restrict__ R, const float* __restrict__ t,
        const float* __restrict__ m, const float* __restrict__ g,
        float4* __restrict__ pws, float4* __restrict__ gws,
        float* __restrict__ ppv,
        unsigned short* __restrict__ paA, unsigned short* __restrict__ pbB,
        unsigned long long* __restrict__ acc, unsigned* __restrict__ counter,
        unsigned* __restrict__ keys, int init_keys) {
    int n = blockIdx.x * 256 + threadIdx.x;
    if (n == 0) { *acc = 0ull; *counter = 0u; }
    if (init_keys) keys[n] = 0xFFFFFFFFu;

    float mx = m[3*n+0], my = m[3*n+1], mz = m[3*n+2];
    float px = fmaf(R[0], mx, fmaf(R[1], my, R[2]*mz)) + t[0];
    float py = fmaf(R[3], mx, fmaf(R[4], my, R[5]*mz)) + t[1];
    float pz = fmaf(R[6], mx, fmaf(R[7], my, R[8]*mz)) + t[2];
    float pp = fmaf(px,px,fmaf(py,py,pz*pz));
    pws[n] = make_float4(-2.f*px, -2.f*py, -2.f*pz, pp);
    ppv[n] = pp;
    float gx = g[3*n+0], gy = g[3*n+1], gz = g[3*n+2];
    float gg = fmaf(gx,gx,fmaf(gy,gy,gz*gz));
    gws[n] = make_float4(gx, gy, gz, gg);

    float Px = -2.f*px, Py = -2.f*py, Pz = -2.f*pz;
    unsigned short phx = bf_rn(Px), phy = bf_rn(Py), phz = bf_rn(Pz);
    unsigned short plx = bf_rn(Px - bf_up(phx)),
                   ply = bf_rn(Py - bf_up(phy)),
                   plz = bf_rn(Pz - bf_up(phz));
    unsigned short ghx = bf_rn(gx), ghy = bf_rn(gy), ghz = bf_rn(gz);
    unsigned short glx = bf_rn(gx - bf_up(ghx)),
                   gly = bf_rn(gy - bf_up(ghy)),
                   glz = bf_rn(gz - bf_up(ghz));
    unsigned short ggh = bf_rn(gg), ggl = bf_rn(gg - bf_up(ggh));
    const unsigned short one = 0x3F80;

    union { unsigned short u[16]; int4 v[2]; } A, B;
    // A (g row): gh gh gh | gh gh gh | gg_h gg_l | gl gl gl | 0...
    A.u[0]=ghx; A.u[1]=ghy; A.u[2]=ghz; A.u[3]=ghx; A.u[4]=ghy; A.u[5]=ghz;
    A.u[6]=ggh; A.u[7]=ggl; A.u[8]=glx; A.u[9]=gly; A.u[10]=glz;
    A.u[11]=0; A.u[12]=0; A.u[13]=0; A.u[14]=0; A.u[15]=0;
    // B (p col): ph ph ph | pl pl pl | 1 1 | ph ph ph | 0...
    B.u[0]=phx; B.u[1]=phy; B.u[2]=phz; B.u[3]=plx; B.u[4]=ply; B.u[5]=plz;
    B.u[6]=one; B.u[7]=one; B.u[8]=phx; B.u[9]=phy; B.u[10]=phz;
    B.u[11]=0; B.u[12]=0; B.u[13]=0; B.u[14]=0; B.u[15]=0;

    int4* pa = (int4*)(paA + (size_t)n * 16);
    int4* pb = (int4*)(pbB + (size_t)n * 16);
    pa[0] = A.v[0]; pa[1] = A.v[1];
    pb[0] = B.v[0]; pb[1] = B.v[1];
}

// 16-value + carry min via v_min3 chains: 9 ops.
__device__ __forceinline__ float tree16c(f32x16 d, float carry) {
    float m0 = min3f(d[0],  d[1],  d[2]);
    float m1 = min3f(d[3],  d[4],  d[5]);
    float m2 = min3f(d[6],  d[7],  d[8]);
    float m3 = min3f(d[9],  d[10], d[11]);
    float m4 = min3f(d[12], d[13], d[14]);
    float m5 = min3f(m4, d[15], carry);
    return min3f(m0, m1, min3f(m2, m3, m5));
}

// MFMA NN: wave owns 128 p-cols (4 B-frags); 16 g-groups per 512-g chunk.
// D-liveness kept to 2 tiles; halves merged via shfl_xor(32) before store.
__global__ __launch_bounds__(256) void k_nn_mfma(
        const unsigned short* __restrict__ paA,
        const unsigned short* __restrict__ pbB,
        float* __restrict__ partial) {
    const int tid = threadIdx.x;
    const int wid = tid >> 6, l = tid & 63;
    const int lc = l & 31, lh = l >> 5;
    const int pbase = blockIdx.x * BLK_P + wid * WAVE_P;
    const int g0 = blockIdx.y * CHUNK_G;

    short8_t B0 = *(const short8_t*)(pbB + (size_t)(pbase +  0 + lc)*16 + lh*8);
    short8_t B1 = *(const short8_t*)(pbB + (size_t)(pbase + 32 + lc)*16 + lh*8);
    short8_t B2 = *(const short8_t*)(pbB + (size_t)(pbase + 64 + lc)*16 + lh*8);
    short8_t B3 = *(const short8_t*)(pbB + (size_t)(pbase + 96 + lc)*16 + lh*8);

    const f32x16 zc = {};
    float rm0 = 3.4e38f, rm1 = 3.4e38f, rm2 = 3.4e38f, rm3 = 3.4e38f;

    const unsigned short* aptr = paA + (size_t)(g0 + lc)*16 + lh*8;
    short8_t a = *(const short8_t*)aptr;
    #pragma unroll 2
    for (int gi = 0; gi < NGROUP; ++gi) {
        short8_t an = (gi + 1 < NGROUP)
                      ? *(const short8_t*)(aptr + (size_t)(gi + 1) * 32 * 16) : a;
        {   // pair 0/1 — only 2 D tiles live at once
            f32x16 d0 = __builtin_amdgcn_mfma_f32_32x32x16_bf16(a, B0, zc, 0, 0, 0);
            f32x16 d1 = __builtin_amdgcn_mfma_f32_32x32x16_bf16(a, B1, zc, 0, 0, 0);
            rm0 = tree16c(d0, rm0);
            rm1 = tree16c(d1, rm1);
        }
        {   // pair 2/3
            f32x16 d2 = __builtin_amdgcn_mfma_f32_32x32x16_bf16(a, B2, zc, 0, 0, 0);
            f32x16 d3 = __builtin_amdgcn_mfma_f32_32x32x16_bf16(a, B3, zc, 0, 0, 0);
            rm2 = tree16c(d2, rm2);
            rm3 = tree16c(d3, rm3);
        }
        a = an;
    }

    // merge row-halves (lanes l and l^32 hold same column, disjoint rows)
    rm0 = fminf(rm0, __shfl_xor(rm0, 32, 64));
    rm1 = fminf(rm1, __shfl_xor(rm1, 32, 64));
    rm2 = fminf(rm2, __shfl_xor(rm2, 32, 64));
    rm3 = fminf(rm3, __shfl_xor(rm3, 32, 64));

    if (lh == 0) {
        float* row = partial + (size_t)blockIdx.y * N_PTS + pbase + lc;
        row[0]  = rm0;
        row[32] = rm1;
        row[64] = rm2;
        row[96] = rm3;
    }
}

// Vector fallback (atomic keys) for small ws.
__global__ __launch_bounds__(256, 4) void k_nn_vec(
        const float4* __restrict__ pws, const float4* __restrict__ gws,
        unsigned* __restrict__ keys) {
    const int tid = threadIdx.x;
    const int pbase = blockIdx.x * 2048;
    const int g0 = blockIdx.y * 64;
    float px[8], py[8], pz[8], pp[8], sm[8];
    #pragma unroll
    for (int k = 0; k < 8; ++k) {
        float4 p = pws[pbase + k*256 + tid];
        px[k]=p.x; py[k]=p.y; pz[k]=p.z; pp[k]=p.w; sm[k]=3.4e38f;
    }
    #pragma unroll 4
    for (int gi = 0; gi < 64; gi += 2) {
        float4 a = gws[g0 + gi];
        float4 b = gws[g0 + gi + 1];
        #pragma unroll
        for (int k = 0; k < 8; ++k) {
            float sa = fmaf(px[k], a.x, fmaf(py[k], a.y, fmaf(pz[k], a.z, a.w)));
            float sb = fmaf(px[k], b.x, fmaf(py[k], b.y, fmaf(pz[k], b.z, b.w)));
            sm[k] = fminf(sm[k], fminf(sa, sb));
        }
    }
    #pragma unroll
    for (int k = 0; k < 8; ++k)
        atomicMin(&keys[pbase + k*256 + tid], enc_f32(sm[k] + pp[k]));
}

// Finalize: per-point min over NROWS rows (+pp), sqrt, wave-sum, fixed-point
// atomic accumulate; last block writes the mean.
template<bool ATOMIC>
__global__ __launch_bounds__(256) void k_fin(
        const float* __restrict__ R, const float* __restrict__ t,
        const float* __restrict__ m, const float* __restrict__ g,
        const float* __restrict__ ppv,
        const float* __restrict__ partial, const int* __restrict__ midx,
        unsigned long long* __restrict__ acc, unsigned* __restrict__ counter,
        float* __restrict__ out) {
    const int tid = threadIdx.x;
    const bool sym = (midx[0] == 0);
    float dis = 0.f;

    if (sym) {
        if (ATOMIC) {
            if (tid < 64) {
                int n = blockIdx.x * 64 + tid;
                dis = sqrtf(fmaxf(dec_f32(((const unsigned*)partial)[n]), 0.f));
            }
        } else {
            const int n = blockIdx.x * 64 + (tid & 63);
            const int q = tid >> 6;                       // row quarter
            float v = 3.4e38f;
            #pragma unroll
            for (int i = 0; i < NROWS/4; ++i)
                v = fminf(v, partial[(size_t)(q*(NROWS/4) + i) * N_PTS + n]);
            __shared__ float sv[256];
            sv[tid] = v;
            __syncthreads();
            if (tid < 64) {
                float d2 = fminf(fminf(sv[tid], sv[tid+64]),
                                 fminf(sv[tid+128], sv[tid+192]));
                dis = sqrtf(fmaxf(ppv[n] + d2, 0.f));
            }
        }
    } else {
        if (tid < 64) {
            int n = blockIdx.x * 64 + tid;
            float mx=m[3*n+0], my=m[3*n+1], mz=m[3*n+2];
            float dx = fmaf(R[0],mx,fmaf(R[1],my,R[2]*mz)) + t[0] - g[3*n+0];
            float dy = fmaf(R[3],mx,fmaf(R[4],my,R[5]*mz)) + t[1] - g[3*n+1];
            float dz = fmaf(R[6],mx,fmaf(R[7],my,R[8]*mz)) + t[2] - g[3*n+2];
            dis = sqrtf(fmaf(dx,dx,fmaf(dy,dy,dz*dz)));
        }
    }

    if (tid < 64) {
        #pragma unroll
        for (int off = 32; off > 0; off >>= 1) dis += __shfl_down(dis, off, 64);
        if (tid == 0) {
            atomicAdd(acc, (unsigned long long)((double)dis * SCALE + 0.5));
            __threadfence();
            unsigned old = atomicAdd(counter, 1u);
            if (old == NFBLK - 1) {
                __threadfence();
                unsigned long long a = atomicAdd(acc, 0ull);
                out[0] = (float)((double)a / SCALE / (double)N_PTS);
            }
        }
    }
}

extern "C" void kernel_launch(void* const* d_in, const int* in_sizes, int n_in,
                              void* d_out, int out_size, void* d_ws, size_t ws_size,
                              hipStream_t stream) {
    const float* R   = (const float*)d_in[0];
    const float* t   = (const float*)d_in[1];
    const float* m   = (const float*)d_in[2];
    const float* g   = (const float*)d_in[3];
    const int* midx  = (const int*)d_in[4];

    char* ws = (char*)d_ws;
    float* out = (float*)d_out;

    const size_t partial_bytes = (size_t)NROWS * N_PTS * 4;   // 2 MB
    // layout: partial | acc/cnt(64B) | pws 256K | gws 256K | pp 64K | paA 512K | pbB 512K
    size_t off = partial_bytes;
    unsigned long long* acc     = (unsigned long long*)(ws + off);
    unsigned*           counter = (unsigned*)(ws + off + 8);
    float4*         pws = (float4*)(ws + off + 64);
    float4*         gws = (float4*)(ws + off + 64 + 262144);
    float*          ppv = (float*)(ws + off + 64 + 524288);
    unsigned short* paA = (unsigned short*)(ws + off + 64 + 524288 + 65536);
    unsigned short* pbB = (unsigned short*)(ws + off + 64 + 524288 + 65536 + 524288);
    const size_t need = off + 64 + 524288 + 65536 + 1048576 + 4096;

    if (ws_size >= need) {
        float* partial = (float*)ws;
        k_prep<<<dim3(N_PTS/256), dim3(256), 0, stream>>>(
            R, t, m, g, pws, gws, ppv, paA, pbB, acc, counter, nullptr, 0);
        k_nn_mfma<<<dim3(NPB, NCH), dim3(256), 0, stream>>>(paA, pbB, partial);
        k_fin<false><<<dim3(NFBLK), dim3(256), 0, stream>>>(
            R, t, m, g, ppv, partial, midx, acc, counter, out);
    } else {
        unsigned* keys = (unsigned*)ws;
        unsigned long long* acc2  = (unsigned long long*)(ws + 65536);
        unsigned*           cnt2  = (unsigned*)(ws + 65536 + 8);
        float4* pws2 = (float4*)(ws + 65536 + 64);
        float4* gws2 = (float4*)(ws + 65536 + 64 + 262144);
        float*  ppv2 = (float*)(ws + 65536 + 64 + 524288);
        unsigned short* paA2 = (unsigned short*)(ws + 65536 + 64 + 524288 + 65536);
        unsigned short* pbB2 = paA2 + 16 * N_PTS;
        k_prep<<<dim3(N_PTS/256), dim3(256), 0, stream>>>(
            R, t, m, g, pws2, gws2, ppv2, paA2, pbB2, acc2, cnt2, keys, 1);
        k_nn_vec<<<dim3(8, 256), dim3(256), 0, stream>>>(pws2, gws2, keys);
        k_fin<true><<<dim3(NFBLK), dim3(256), 0, stream>>>(
            R, t, m, g, ppv2, (float*)keys, midx, acc2, cnt2, out);
    }
}